// Round 13
// baseline (811.458 us; speedup 1.0000x reference)
//
#include <hip/hip_runtime.h>
#include <hip/hip_bf16.h>
#include <stdint.h>

// ---------------------------------------------------------------------------
// FluxSingleStreamBlock  B=1 L=2048 HID=3072 NH=24 HD=128 MLP=12288
// GEMM: 256x256 tile, BK=64, 8 waves, quadrant 8-phase schedule (R12 form).
// R13: independent BW-bound kernels fused into 3 block-role dispatches:
//   fused0 = convT(fc1)+convT(qkv-lo)+convT(qkv-scr)+mod_partial
//   fused1 = convT(fc2)+vtrans+qknorm      (after EPI=2; G & P0 lifetimes ok)
//   fused2 = attn+convT(w_out)             (P0 dead after fused1)
// ---------------------------------------------------------------------------

typedef __bf16 bf16;
typedef bf16 bf16x2 __attribute__((ext_vector_type(2)));
typedef bf16 bf16x4 __attribute__((ext_vector_type(4)));
typedef bf16 bf16x8 __attribute__((ext_vector_type(8)));
typedef float f32x4 __attribute__((ext_vector_type(4)));

#define L_SEQ 2048
#define HIDD  3072
#define NHH   24
#define HDD   128
#define MLPD  12288
#define N3Q   9216

struct PB { bf16* p[4]; };

__device__ __forceinline__ void gload_lds16(const bf16* g, bf16* l) {
  __builtin_amdgcn_global_load_lds(
      (const __attribute__((address_space(1))) unsigned int*)g,
      (__attribute__((address_space(3))) unsigned int*)l, 16, 0, 0);
}

__device__ __forceinline__ float gelu_tanh(float x) {
  float z = 0.7978845608028654f * (x + 0.044715f * x * x * x);
  float t = 1.f - 2.f / (__expf(2.f * z) + 1.f);   // tanh(z), inf-safe
  return 0.5f * x * (1.f + t);
}

// ---------------- role bodies ----------------------------------------------
// convT tile: src [K][N] f32 -> dst [N'][K] bf16. pad 73 (conflict-free).
__device__ __forceinline__ void convT_tile(
    const float* __restrict__ src, bf16* __restrict__ dst, int K, int N,
    int bx, int by, bf16* tl) {
  int n0 = bx * 64, k0 = by * 64;
  int t = threadIdx.x;
#pragma unroll
  for (int p = 0; p < 4; ++p) {
    int idx = p * 256 + t;
    int kr = idx >> 4, c4 = (idx & 15) << 2;
    float4 v = *(const float4*)(src + (size_t)(k0 + kr) * N + n0 + c4);
    bf16x4 b;
    b[0] = (bf16)v.x; b[1] = (bf16)v.y; b[2] = (bf16)v.z; b[3] = (bf16)v.w;
    *(bf16x4*)(tl + kr * 73 + c4) = b;
  }
  __syncthreads();
#pragma unroll
  for (int p = 0; p < 2; ++p) {
    int idx = p * 256 + t;
    int nr = idx >> 3, c = idx & 7;
    bf16x8 o;
#pragma unroll
    for (int j = 0; j < 8; ++j) o[j] = tl[(c * 8 + j) * 73 + nr];
    *(bf16x8*)(dst + (size_t)(n0 + nr) * K + k0 + c * 8) = o;
  }
}

__device__ __forceinline__ void mod_partial_body(
    const float* __restrict__ vec, const float* __restrict__ w_mod,
    float* __restrict__ part, int bx, int by, float* sv) {
  int i0 = by * 256;
  {
    float xv = vec[i0 + threadIdx.x];
    sv[threadIdx.x] = xv / (1.f + __expf(-xv));
  }
  __syncthreads();
  int j = bx * 256 + threadIdx.x;
  float acc = 0.f;
#pragma unroll 8
  for (int i = 0; i < 256; ++i)
    acc += sv[i] * w_mod[(size_t)(i0 + i) * N3Q + j];
  part[by * N3Q + j] = acc;
}

__device__ __forceinline__ void qknorm_body(
    const bf16* __restrict__ P, const float* __restrict__ b_qkv,
    const float* __restrict__ pe, const float* __restrict__ qw,
    const float* __restrict__ kw, bf16* __restrict__ qb,
    bf16* __restrict__ kb, int blk) {
  int t = threadIdx.x, lane = t & 63, w = t >> 6;
  int pair = blk * 4 + w;
  int h = pair % NHH, l = pair / NHH;
  size_t qi = (size_t)l * N3Q + h * HDD + 2 * lane;
  size_t ob = (size_t)l * HIDD + h * HDD + 2 * lane;
  float4 f = *(const float4*)(pe + (size_t)l * 256 + lane * 4);
  float2 wq = *(const float2*)(qw + 2 * lane);
  float2 wk = *(const float2*)(kw + 2 * lane);
  {
    bf16x2 a = *(const bf16x2*)(P + qi);
    float2 bq = *(const float2*)(b_qkv + h * HDD + 2 * lane);
    float x0 = (float)a[0] + bq.x;
    float x1 = (float)a[1] + bq.y;
    float ss = x0 * x0 + x1 * x1;
#pragma unroll
    for (int o = 32; o >= 1; o >>= 1) ss += __shfl_xor(ss, o);
    float rs = rsqrtf(ss * (1.f / HDD) + 1.1920929e-7f);
    x0 *= rs * wq.x; x1 *= rs * wq.y;
    const float qs = 0.08838834764831845f;  // 1/sqrt(128)
    bf16x2 ov;
    ov[0] = (bf16)((f.x * x0 + f.y * x1) * qs);
    ov[1] = (bf16)((f.z * x0 + f.w * x1) * qs);
    *(bf16x2*)(qb + ob) = ov;
  }
  {
    bf16x2 a = *(const bf16x2*)(P + qi + HIDD);
    float2 bk = *(const float2*)(b_qkv + HIDD + h * HDD + 2 * lane);
    float x0 = (float)a[0] + bk.x;
    float x1 = (float)a[1] + bk.y;
    float ss = x0 * x0 + x1 * x1;
#pragma unroll
    for (int o = 32; o >= 1; o >>= 1) ss += __shfl_xor(ss, o);
    float rs = rsqrtf(ss * (1.f / HDD) + 1.1920929e-7f);
    x0 *= rs * wk.x; x1 *= rs * wk.y;
    bf16x2 ov;
    ov[0] = (bf16)(f.x * x0 + f.y * x1);
    ov[1] = (bf16)(f.z * x0 + f.w * x1);
    *(bf16x2*)(kb + ob) = ov;
  }
}

__device__ __forceinline__ void vtrans_body(
    const bf16* __restrict__ P, const float* __restrict__ b_qkv,
    bf16* __restrict__ vt, int lt, int h, bf16* tl) {
  int t = threadIdx.x;
#pragma unroll
  for (int p = 0; p < 8; ++p) {
    int idx = p * 256 + t;
    int i = idx >> 4, c = idx & 15;
    size_t gi = (size_t)(lt * 128 + i) * N3Q + 2 * HIDD + h * HDD + c * 8;
    bf16x8 a = *(const bf16x8*)(P + gi);
    bf16x8 val;
#pragma unroll
    for (int e = 0; e < 8; ++e)
      val[e] = (bf16)((float)a[e] + b_qkv[2 * HIDD + h * HDD + c * 8 + e]);
    *(bf16x8*)(tl + i * 128 + ((c ^ (i & 15)) << 3)) = val;
  }
  __syncthreads();
#pragma unroll
  for (int p = 0; p < 8; ++p) {
    int idx = p * 256 + t;
    int j = idx >> 4, i8 = (idx & 15) << 3;
    bf16x8 o;
#pragma unroll
    for (int e = 0; e < 8; ++e) {
      int row = i8 + e;
      o[e] = tl[row * 128 + ((((j >> 3) ^ (row & 15)) << 3) | (j & 7))];
    }
    *(bf16x8*)(vt + ((size_t)h * HDD + j) * L_SEQ + lt * 128 + i8) = o;
  }
}

__device__ __forceinline__ void attn_body(
    const bf16* __restrict__ q, const bf16* __restrict__ k,
    const bf16* __restrict__ vt, bf16* __restrict__ out, int qt, int h,
    char* smem) {
  bf16* Ks = (bf16*)smem;                 // 64*128 = 16384 B
  bf16* Vs = (bf16*)(smem + 16384);       // 128*64 = 16384 B
  int tid = threadIdx.x, lane = tid & 63, w = tid >> 6;
  int g = lane >> 4, r16 = lane & 15;
  bf16* ps = (bf16*)(smem + 32768) + w * 1152;  // per-wave 16*72
  int qbase = qt * 64 + w * 16;

  bf16x8 qreg[4];
  const bf16* qrow = q + (size_t)(qbase + r16) * HIDD + h * HDD;
#pragma unroll
  for (int c = 0; c < 4; ++c) qreg[c] = *(const bf16x8*)(qrow + c * 32 + g * 8);

  f32x4 acc[8] = {};
  float m_run = -3.0e38f, l_run = 0.f;

  for (int kv0 = 0; kv0 < L_SEQ; kv0 += 64) {
    __syncthreads();
#pragma unroll
    for (int p = 0; p < 4; ++p) {
      int ci = p * 256 + tid;
      {
        int rr = ci >> 4, cc = ci & 15;
        gload_lds16(k + (size_t)(kv0 + rr) * HIDD + h * HDD +
                        ((cc ^ (rr & 15)) << 3),
                    Ks + ((p * 4 + w) << 9));
      }
      {
        int rr = ci >> 3, cc = ci & 7;
        gload_lds16(vt + ((size_t)h * HDD + rr) * L_SEQ + kv0 +
                        ((cc ^ (rr & 7)) << 3),
                    Vs + ((p * 4 + w) << 9));
      }
    }
    __syncthreads();

    f32x4 st[4] = {};
#pragma unroll
    for (int m4 = 0; m4 < 4; ++m4) {
#pragma unroll
      for (int c = 0; c < 4; ++c) {
        int rr = m4 * 16 + r16;
        bf16x8 kf =
            *(const bf16x8*)(Ks + rr * 128 + (((c * 4 + g) ^ (rr & 15)) << 3));
        st[m4] =
            __builtin_amdgcn_mfma_f32_16x16x32_bf16(kf, qreg[c], st[m4], 0, 0, 0);
      }
    }
    float cmax = -3.0e38f;
#pragma unroll
    for (int m4 = 0; m4 < 4; ++m4)
#pragma unroll
      for (int r = 0; r < 4; ++r) cmax = fmaxf(cmax, st[m4][r]);
    cmax = fmaxf(cmax, __shfl_xor(cmax, 16));
    cmax = fmaxf(cmax, __shfl_xor(cmax, 32));
    float m_new = fmaxf(m_run, cmax);
    float corr = __expf(m_run - m_new);
    float psum = 0.f;
#pragma unroll
    for (int m4 = 0; m4 < 4; ++m4) {
      bf16x4 pk;
#pragma unroll
      for (int r = 0; r < 4; ++r) {
        float pv = __expf(st[m4][r] - m_new);
        psum += pv;
        pk[r] = (bf16)pv;
      }
      *(bf16x4*)(ps + r16 * 72 + m4 * 16 + g * 4) = pk;
    }
    psum += __shfl_xor(psum, 16);
    psum += __shfl_xor(psum, 32);
    l_run = l_run * corr + psum;
    m_run = m_new;
    float corr_r[4];
#pragma unroll
    for (int r = 0; r < 4; ++r) corr_r[r] = __shfl(corr, g * 4 + r);
#pragma unroll
    for (int nt = 0; nt < 8; ++nt)
#pragma unroll
      for (int r = 0; r < 4; ++r) acc[nt][r] *= corr_r[r];
#pragma unroll
    for (int ks = 0; ks < 2; ++ks) {
      bf16x8 pf = *(const bf16x8*)(ps + r16 * 72 + ks * 32 + g * 8);
#pragma unroll
      for (int nt = 0; nt < 8; ++nt) {
        int rr = nt * 16 + r16;
        bf16x8 vf =
            *(const bf16x8*)(Vs + rr * 64 + (((ks * 4 + g) ^ (rr & 7)) << 3));
        acc[nt] = __builtin_amdgcn_mfma_f32_16x16x32_bf16(pf, vf, acc[nt], 0, 0, 0);
      }
    }
  }
  float inv = 1.f / l_run;
  float inv_r[4];
#pragma unroll
  for (int r = 0; r < 4; ++r) inv_r[r] = __shfl(inv, g * 4 + r);
#pragma unroll
  for (int nt = 0; nt < 8; ++nt)
#pragma unroll
    for (int r = 0; r < 4; ++r)
      out[(size_t)(qbase + g * 4 + r) * HIDD + h * HDD + nt * 16 + r16] =
          (bf16)(acc[nt][r] * inv_r[r]);
}

// ---------------- fused dispatches ------------------------------------------
__global__ __launch_bounds__(256) void fused0(
    const float* __restrict__ vec, const float* __restrict__ w_mod,
    float* __restrict__ part, const float* __restrict__ w_qkv,
    const float* __restrict__ w_fc1, bf16* __restrict__ wtQlo,
    bf16* __restrict__ wtScr, bf16* __restrict__ wtG) {
  __shared__ __align__(16) char smem[64 * 73 * 2];
  int f = (int)blockIdx.x;
  if (f < 9216) {
    convT_tile(w_fc1, wtG, 3072, 12288, f % 192, f / 192, (bf16*)smem);
  } else if (f < 15360) {
    f -= 9216;
    convT_tile(w_qkv, wtQlo, 3072, 9216, f % 128, f / 128, (bf16*)smem);
  } else if (f < 16128) {
    f -= 15360;
    convT_tile(w_qkv + 8192, wtScr, 3072, 9216, f % 16, f / 16, (bf16*)smem);
  } else {
    f -= 16128;
    mod_partial_body(vec, w_mod, part, f % 36, f / 36, (float*)smem);
  }
}

__global__ __launch_bounds__(256) void fused1(
    const float* __restrict__ w_fc2, bf16* __restrict__ wtG,
    const bf16* __restrict__ P0, const float* __restrict__ b_qkv,
    const float* __restrict__ pe, const float* __restrict__ qw,
    const float* __restrict__ kw, bf16* __restrict__ qb,
    bf16* __restrict__ kbuf, bf16* __restrict__ vt) {
  __shared__ __align__(16) char smem[128 * 128 * 2];
  int f = (int)blockIdx.x;
  if (f < 9216) {
    convT_tile(w_fc2, wtG, 12288, 3072, f % 48, f / 48, (bf16*)smem);
  } else if (f < 9600) {
    f -= 9216;
    vtrans_body(P0, b_qkv, vt, f % 16, f / 16, (bf16*)smem);
  } else {
    f -= 9600;
    qknorm_body(P0, b_qkv, pe, qw, kw, qb, kbuf, f);
  }
}

__global__ __launch_bounds__(256) void fused2(
    const bf16* __restrict__ qb, const bf16* __restrict__ kbuf,
    const bf16* __restrict__ vt, bf16* __restrict__ att,
    const float* __restrict__ w_out, bf16* __restrict__ wtO) {
  __shared__ __align__(16) char smem[41984];  // attn: 16K+16K+9.2K
  int f = (int)blockIdx.x;
  if (f < 768) {
    attn_body(qb, kbuf, vt, att, f & 31, f >> 5, smem);
  } else {
    f -= 768;
    convT_tile(w_out, wtO, 3072, 3072, f % 48, f / 48, (bf16*)smem);
  }
}

__global__ __launch_bounds__(256) void mod_reduce(
    const float* __restrict__ part, const float* __restrict__ b_mod,
    float* __restrict__ mod) {
  int j = blockIdx.x * 256 + threadIdx.x;
  float s = b_mod[j];
#pragma unroll
  for (int p = 0; p < 12; ++p) s += part[p * N3Q + j];
  mod[j] = s;
}

// ---------------- K2: layernorm + modulate -> x_mod bf16 --------------------
__global__ __launch_bounds__(256) void ln_mod_k(
    const float* __restrict__ x, const float* __restrict__ mod,
    bf16* __restrict__ xm) {
  __shared__ float sb[4];
  int l = blockIdx.x, t = threadIdx.x;
  const float* xr = x + (size_t)l * HIDD;
  float4 v[3];
  float s = 0.f;
#pragma unroll
  for (int p = 0; p < 3; ++p) {
    v[p] = *(const float4*)(xr + p * 1024 + t * 4);
    s += v[p].x + v[p].y + v[p].z + v[p].w;
  }
#pragma unroll
  for (int o = 32; o >= 1; o >>= 1) s += __shfl_xor(s, o);
  if (!(t & 63)) sb[t >> 6] = s;
  __syncthreads();
  float mean = (sb[0] + sb[1] + sb[2] + sb[3]) * (1.f / HIDD);
  __syncthreads();
  float vs = 0.f;
#pragma unroll
  for (int p = 0; p < 3; ++p) {
    float a = v[p].x - mean, b = v[p].y - mean, c = v[p].z - mean,
          d = v[p].w - mean;
    vs += a * a + b * b + c * c + d * d;
  }
#pragma unroll
  for (int o = 32; o >= 1; o >>= 1) vs += __shfl_xor(vs, o);
  if (!(t & 63)) sb[t >> 6] = vs;
  __syncthreads();
  float var = (sb[0] + sb[1] + sb[2] + sb[3]) * (1.f / HIDD);
  float rs = rsqrtf(var + 1e-6f);
#pragma unroll
  for (int p = 0; p < 3; ++p) {
    int j = p * 1024 + t * 4;
    float4 sc = *(const float4*)(mod + HIDD + j);
    float4 sh = *(const float4*)(mod + j);
    bf16x4 o;
    o[0] = (bf16)((v[p].x - mean) * rs * (1.f + sc.x) + sh.x);
    o[1] = (bf16)((v[p].y - mean) * rs * (1.f + sc.y) + sh.y);
    o[2] = (bf16)((v[p].z - mean) * rs * (1.f + sc.z) + sh.z);
    o[3] = (bf16)((v[p].w - mean) * rs * (1.f + sc.w) + sh.w);
    *(bf16x4*)(xm + (size_t)l * HIDD + j) = o;
  }
}

// ---------------- GEMM 256x256, BK=64, 8 waves, quadrant 8-phase ------------
template <int EPI>
__global__ __launch_bounds__(512, 2) void gemm256(
    const bf16* __restrict__ A, const bf16* __restrict__ BT,
    const float* __restrict__ bias, int lda, int klen, int gy, int gz,
    PB dst, bf16* __restrict__ o1, const bf16* __restrict__ BT2,
    const bf16* __restrict__ BT3, float* __restrict__ o32) {
  __shared__ bf16 LA[2][2][8192];   // [buf][half: 128 rows x 64 k]
  __shared__ bf16 LB[2][2][8192];
  const int tid = threadIdx.x;
  const int w = tid >> 6, lane = tid & 63;
  const int wm = w >> 2, wn = w & 3;
  const int g = lane >> 4, r16 = lane & 15;
  const int hb = wn >> 1, brow = (wn & 1) * 64;

  // T1: bijective chunked XCD swizzle (grid % 8 == 0 guaranteed)
  const int nwg = 8 * gy * gz;
  int id = (int)blockIdx.x;
  int sw = (id & 7) * (nwg >> 3) + (id >> 3);
  const int bx = sw & 7;
  const int rem = sw >> 3;
  const int by = rem % gy;
  const int bz = rem / gy;

  const int row0 = bx * 256, col0 = by * 256;

  const int s_r = tid >> 3, s_c = tid & 7;
  const int swzoff = (s_c ^ (s_r & 7)) << 3;

  int lda_eff = lda;
  const bf16* Abase = A;
  const bf16* Bbase = BT;
  size_t kb2 = 0;
  int bcol = col0;
  if (EPI == 2) {
    if (by >= 36)      { Bbase = BT3; bcol = col0 - 9216; }
    else if (by >= 32) { Bbase = BT2; bcol = col0 - 8192; }
  } else if (EPI == 3) {
    if (bz != 0) {
      lda_eff = MLPD;
      Abase = BT3;            // mlpF (fc2 A)
      Bbase = BT2;            // w_fc2^T
      kb2 = (size_t)(bz - 1) * 3072;
    }
  }
  const bf16* gA = Abase + (size_t)(row0 + s_r) * lda_eff + kb2 + swzoff;
  const bf16* gB = Bbase + (size_t)(bcol + s_r) * lda_eff + kb2 + swzoff;
  const int wofs = w * 512;

#define STG_A(buf, h, t)                                                       \
  do {                                                                         \
    gload_lds16(gA + (size_t)((h) * 128) * lda_eff + (size_t)(t) * 64,         \
                &LA[buf][h][wofs]);                                            \
    gload_lds16(gA + (size_t)((h) * 128 + 64) * lda_eff + (size_t)(t) * 64,    \
                &LA[buf][h][4096 + wofs]);                                     \
  } while (0)
#define STG_B(buf, h, t)                                                       \
  do {                                                                         \
    gload_lds16(gB + (size_t)((h) * 128) * lda_eff + (size_t)(t) * 64,         \
                &LB[buf][h][wofs]);                                            \
    gload_lds16(gB + (size_t)((h) * 128 + 64) * lda_eff + (size_t)(t) * 64,    \
                &LB[buf][h][4096 + wofs]);                                     \
  } while (0)
#define SB0() __builtin_amdgcn_sched_barrier(0)
#define RD_A4(DST, LAP, MB)                                                    \
  _Pragma("unroll") for (int m_ = 0; m_ < 4; ++m_)                             \
  _Pragma("unroll") for (int kk_ = 0; kk_ < 2; ++kk_)                          \
      DST[m_][kk_] = *(const bf16x8*)((LAP) + (((MB) + m_) * 16 + r16) * 64 +  \
                                      (((kk_ * 4 + g) ^ (r16 & 7)) << 3));
#define RD_B2(DST, LBP, NB)                                                    \
  _Pragma("unroll") for (int n_ = 0; n_ < 2; ++n_)                             \
  _Pragma("unroll") for (int kk_ = 0; kk_ < 2; ++kk_)                          \
      DST[n_][kk_] = *(const bf16x8*)(                                         \
          (LBP) + (brow + ((NB) + n_) * 16 + r16) * 64 +                       \
          (((kk_ * 4 + g) ^ (r16 & 7)) << 3));
#define QUAD(AF, BF, MB, NB)                                                   \
  do {                                                                         \
    __builtin_amdgcn_s_setprio(1);                                             \
    _Pragma("unroll") for (int kk_ = 0; kk_ < 2; ++kk_)                        \
    _Pragma("unroll") for (int m_ = 0; m_ < 4; ++m_)                           \
    _Pragma("unroll") for (int n_ = 0; n_ < 2; ++n_)                           \
        acc[(MB) + m_][(NB) + n_] = __builtin_amdgcn_mfma_f32_16x16x32_bf16(   \
            AF[m_][kk_], BF[n_][kk_], acc[(MB) + m_][(NB) + n_], 0, 0, 0);     \
    __builtin_amdgcn_s_setprio(0);                                             \
  } while (0)

  // Race-free stage ring (reads of a half complete barrier-before its stage):
  //   a: B1(T1)->TB^1   b: (none)   c: A0(T2),A1(T2)->TB   d: B0(T2)->TB
#define GROUP(TB, T1, T2)                                                      \
  do {                                                                         \
    const bf16* la = &LA[TB][wm][0];                                           \
    const bf16* lb = &LB[TB][hb][0];                                           \
    bf16x8 aL[4][2], aH[4][2], bL[2][2], bH[2][2];                             \
    /* P-a: 12 ds_reads, stage B1(T1) */                                       \
    RD_A4(aL, la, 0);                                                          \
    RD_B2(bL, lb, 0);                                                          \
    if ((T1) < nk) STG_B(TB ^ 1, 1, T1);                                       \
    __builtin_amdgcn_s_barrier();                                              \
    SB0();                                                                     \
    QUAD(aL, bL, 0, 0);                                                        \
    __builtin_amdgcn_s_barrier();                                              \
    /* P-b: 8 ds_reads, no stage (LA[TB] still being read) */                  \
    RD_A4(aH, la, 4);                                                          \
    __builtin_amdgcn_s_barrier();                                              \
    SB0();                                                                     \
    QUAD(aH, bL, 4, 0);                                                        \
    __builtin_amdgcn_s_barrier();                                              \
    /* P-c: 4 ds_reads, stage A0(T2),A1(T2) (LA[TB] dead since P-b barrier) */ \
    RD_B2(bH, lb, 2);                                                          \
    if ((T2) < nk) { STG_A(TB, 0, T2); STG_A(TB, 1, T2); }                     \
    __builtin_amdgcn_s_barrier();                                              \
    SB0();                                                                     \
    QUAD(aL, bH, 0, 2);                                                        \
    __builtin_amdgcn_s_barrier();                                              \
    /* P-d: no reads, stage B0(T2) (LB[TB] dead since P-c barrier), vmcnt */   \
    if ((T2) < nk) {                                                           \
      STG_B(TB, 0, T2);                                                        \
      asm volatile("s_waitcnt vmcnt(6)" ::: "memory");                         \
    } else {                                                                   \
      asm volatile("s_waitcnt vmcnt(0)" ::: "memory");                         \
    }                                                                          \
    __builtin_amdgcn_s_barrier();                                              \
    SB0();                                                                     \
    QUAD(aH, bH, 4, 2);                                                        \
    __builtin_amdgcn_s_barrier();                                              \
  } while (0)

  f32x4 acc[8][4] = {};
  const int nk = klen >> 6;   // 48 for all call sites

  // prologue: tile0 complete + A0,A1,B0 of tile1 (B1(1) staged at first P-a);
  // vmcnt(6) waits 14-6=8 oldest = ALL of tile0.
  STG_A(0, 0, 0); STG_A(0, 1, 0); STG_B(0, 0, 0); STG_B(0, 1, 0);
  STG_A(1, 0, 1); STG_A(1, 1, 1); STG_B(1, 0, 1);
  asm volatile("s_waitcnt vmcnt(6)" ::: "memory");
  __builtin_amdgcn_s_barrier();

  for (int t = 0; t < nk; t += 2) {
    GROUP(0, t + 1, t + 2);
    GROUP(1, t + 2, t + 3);
  }
#undef STG_A
#undef STG_B
#undef SB0
#undef RD_A4
#undef RD_B2
#undef QUAD
#undef GROUP

  if (EPI == 2 && by < 36) {
    // qkv half: raw bf16, stride 9216
    bf16* dp = dst.p[0];
#pragma unroll
    for (int m = 0; m < 8; ++m) {
      int row = row0 + wm * 128 + m * 16 + g * 4;
#pragma unroll
      for (int n = 0; n < 4; ++n) {
        int col = col0 + wn * 64 + n * 16 + r16;
#pragma unroll
        for (int r = 0; r < 4; ++r)
          dp[(size_t)(row + r) * N3Q + col] = (bf16)acc[m][n][r];
      }
    }
  } else if (EPI == 2) {
    // fc1 half: bias+gelu, stride 12288
    bf16* dp = o1;
#pragma unroll
    for (int m = 0; m < 8; ++m) {
      int row = row0 + wm * 128 + m * 16 + g * 4;
#pragma unroll
      for (int n = 0; n < 4; ++n) {
        int col = col0 - 9216 + wn * 64 + n * 16 + r16;
        float bv = bias[col];
#pragma unroll
        for (int r = 0; r < 4; ++r)
          dp[(size_t)(row + r) * MLPD + col] = (bf16)gelu_tanh(acc[m][n][r] + bv);
      }
    }
  } else if (EPI == 3 && bz == 0) {
    // out-proj: raw f32 sums -> o32 (final adds b_out)
#pragma unroll
    for (int m = 0; m < 8; ++m) {
      int row = row0 + wm * 128 + m * 16 + g * 4;
#pragma unroll
      for (int n = 0; n < 4; ++n) {
        int col = col0 + wn * 64 + n * 16 + r16;
#pragma unroll
        for (int r = 0; r < 4; ++r)
          o32[(size_t)(row + r) * HIDD + col] = acc[m][n][r];
      }
    }
  } else {
    // fc2 partial bz-1: bf16, stride 3072
    bf16* dp = dst.p[bz - 1];
#pragma unroll
    for (int m = 0; m < 8; ++m) {
      int row = row0 + wm * 128 + m * 16 + g * 4;
#pragma unroll
      for (int n = 0; n < 4; ++n) {
        int col = col0 + wn * 64 + n * 16 + r16;
#pragma unroll
        for (int r = 0; r < 4; ++r)
          dp[(size_t)(row + r) * HIDD + col] = (bf16)acc[m][n][r];
      }
    }
  }
}

// -------- final: out = x + gate*(dacc + b_out + sum4(pF) + b_fc2) -----------
__global__ __launch_bounds__(256) void final_k(
    const float* __restrict__ x, PB ps, const float* __restrict__ mod,
    const float* __restrict__ b_out, const float* __restrict__ b_fc2,
    float* __restrict__ out) {
  int l = blockIdx.x, t = threadIdx.x;
#pragma unroll
  for (int p = 0; p < 3; ++p) {
    int c = p * 1024 + t * 4;
    size_t idx = (size_t)l * HIDD + c;
    float4 xv = *(const float4*)(x + idx);
    float4 gv = *(const float4*)(mod + 2 * HIDD + c);
    float4 bo = *(const float4*)(b_out + c);
    float4 bf = *(const float4*)(b_fc2 + c);
    float4 da = *(const float4*)(out + idx);  // out-proj blocks wrote here
    float a0 = da.x + bo.x + bf.x, a1 = da.y + bo.y + bf.y;
    float a2 = da.z + bo.z + bf.z, a3 = da.w + bo.w + bf.w;
#pragma unroll
    for (int i = 0; i < 4; ++i) {
      bf16x4 v = *(const bf16x4*)(ps.p[i] + idx);
      a0 += (float)v[0]; a1 += (float)v[1];
      a2 += (float)v[2]; a3 += (float)v[3];
    }
    float4 o;
    o.x = xv.x + gv.x * a0;
    o.y = xv.y + gv.y * a1;
    o.z = xv.z + gv.z * a2;
    o.w = xv.w + gv.w * a3;
    *(float4*)(out + idx) = o;
  }
}

// ---------------------------------------------------------------------------
extern "C" void kernel_launch(void* const* d_in, const int* in_sizes, int n_in,
                              void* d_out, int out_size, void* d_ws,
                              size_t ws_size, hipStream_t stream) {
  const float* x     = (const float*)d_in[0];
  const float* vec   = (const float*)d_in[1];
  const float* pe    = (const float*)d_in[2];
  const float* w_mod = (const float*)d_in[3];
  const float* b_mod = (const float*)d_in[4];
  const float* w_qkv = (const float*)d_in[5];
  const float* b_qkv = (const float*)d_in[6];
  const float* w_fc1 = (const float*)d_in[7];
  const float* b_fc1 = (const float*)d_in[8];
  const float* w_fc2 = (const float*)d_in[9];
  const float* b_fc2 = (const float*)d_in[10];
  const float* w_out = (const float*)d_in[11];
  const float* b_out = (const float*)d_in[12];
  const float* qw    = (const float*)d_in[13];
  const float* kw    = (const float*)d_in[14];
  float* out = (float*)d_out;

  char* ws = (char*)d_ws;
  float* mod  = (float*)(ws + 0);               // 36864 (pad to 64K)
  bf16* xmod  = (bf16*)(ws + 65536);            // A: 12.58M -> 12648448
  bf16* qb    = (bf16*)(ws + 12648448);         // B
  bf16* kbuf  = (bf16*)(ws + 25231360);         // C
  bf16* vt    = (bf16*)(ws + 37814272);         // D
  bf16* att   = (bf16*)(ws + 50397184);         // E
  bf16* mlpF  = (bf16*)(ws + 62980096);         // F: 50.33M -> 113311744
  bf16* wt    = (bf16*)(ws + 113311744);        // G: 75.5M  -> 188809216
  bf16* P0    = (bf16*)(ws + 188809216);        // H: 37.75M -> 226557952
  float* part = (float*)(ws + 188809216);       // overlay H (early)
  bf16* wtQlo = qb;                             // B..E span: 8192 rows x 3072
  bf16* wtScr = (bf16*)out;                     // d_out scratch: 1024 rows
  bf16* wtO   = P0;                             // H-head: w_out^T (18.9 MB)

  // D0: convT(fc1->G) | convT(qkv-lo->B..E) | convT(qkv-scr->d_out) | mod_partial->H
  fused0<<<16560, 256, 0, stream>>>(vec, w_mod, part, w_qkv, w_fc1, wtQlo,
                                    wtScr, wt);
  mod_reduce<<<36, 256, 0, stream>>>(part, b_mod, mod);
  ln_mod_k<<<2048, 256, 0, stream>>>(x, mod, xmod);

  // EPI=2: combined qkv+fc1 -> P0(H) raw + mlpF(F) gelu
  PB Pc = {}; Pc.p[0] = P0;
  gemm256<2><<<672, 512, 0, stream>>>(xmod, wtQlo, b_fc1, 3072, 3072, 84, 1,
                                      Pc, mlpF, wtScr, wt, nullptr);

  // D1: convT(fc2->G) | vtrans | qknorm   (G & wtQlo dead; P0 read-only)
  fused1<<<21888, 256, 0, stream>>>(w_fc2, wt, P0, b_qkv, pe, qw, kw, qb,
                                    kbuf, vt);

  // D2: attn | convT(w_out->H-head)       (P0 dead after D1)
  fused2<<<3072, 256, 0, stream>>>(qb, kbuf, vt, att, w_out, wtO);

  // EPI=3: out-proj (bz=0, f32->d_out) + fc2 SK4 (bf16 partials A..D)
  PB Pf = {};
  Pf.p[0] = xmod; Pf.p[1] = qb; Pf.p[2] = kbuf; Pf.p[3] = vt;
  gemm256<3><<<480, 512, 0, stream>>>(att, wtO, nullptr, 3072, 3072, 12, 5,
                                      Pf, nullptr, wt, mlpF, out);

  final_k<<<2048, 256, 0, stream>>>(x, Pf, mod, b_out, b_fc2, out);
}

// Round 14
// 811.110 us; speedup vs baseline: 1.0004x; 1.0004x over previous
//
#include <hip/hip_runtime.h>
#include <hip/hip_bf16.h>
#include <stdint.h>

// ---------------------------------------------------------------------------
// FluxSingleStreamBlock  B=1 L=2048 HID=3072 NH=24 HD=128 MLP=12288
// GEMM: 256x256 tile, BK=64, 8 waves, quadrant 8-phase schedule with
// race-free stage ring: a:B1(t+1) b:- c:A0,A1(t+2) d:B0(t+2)+vmcnt(6).
// R14: no post-barrier sched_barrier — register-only MFMAs may hoist across
// s_barrier (safe: cross-wave LDS safety depends only on mem-op issue order,
// which barriers enforce; MFMA operands are same-wave lgkm-waited).
// Dispatch layout = R12 (unfused; R13 fusion was neutral-negative).
// ---------------------------------------------------------------------------

typedef __bf16 bf16;
typedef bf16 bf16x2 __attribute__((ext_vector_type(2)));
typedef bf16 bf16x4 __attribute__((ext_vector_type(4)));
typedef bf16 bf16x8 __attribute__((ext_vector_type(8)));
typedef float f32x4 __attribute__((ext_vector_type(4)));

#define L_SEQ 2048
#define HIDD  3072
#define NHH   24
#define HDD   128
#define MLPD  12288
#define N3Q   9216

struct PB { bf16* p[4]; };

__device__ __forceinline__ void gload_lds16(const bf16* g, bf16* l) {
  __builtin_amdgcn_global_load_lds(
      (const __attribute__((address_space(1))) unsigned int*)g,
      (__attribute__((address_space(3))) unsigned int*)l, 16, 0, 0);
}

__device__ __forceinline__ float gelu_tanh(float x) {
  float z = 0.7978845608028654f * (x + 0.044715f * x * x * x);
  float t = 1.f - 2.f / (__expf(2.f * z) + 1.f);   // tanh(z), inf-safe
  return 0.5f * x * (1.f + t);
}

// ---------------- K1a: mod partial GEMV: silu(vec) @ w_mod ------------------
__global__ __launch_bounds__(256) void mod_partial(
    const float* __restrict__ vec, const float* __restrict__ w_mod,
    float* __restrict__ part) {
  __shared__ float sv[256];
  int y = blockIdx.y;
  int i0 = y * 256;
  {
    float xv = vec[i0 + threadIdx.x];
    sv[threadIdx.x] = xv / (1.f + __expf(-xv));
  }
  __syncthreads();
  int j = blockIdx.x * 256 + threadIdx.x;
  float acc = 0.f;
#pragma unroll 8
  for (int i = 0; i < 256; ++i)
    acc += sv[i] * w_mod[(size_t)(i0 + i) * N3Q + j];
  part[y * N3Q + j] = acc;
}

__global__ __launch_bounds__(256) void mod_reduce(
    const float* __restrict__ part, const float* __restrict__ b_mod,
    float* __restrict__ mod) {
  int j = blockIdx.x * 256 + threadIdx.x;
  float s = b_mod[j];
#pragma unroll
  for (int p = 0; p < 12; ++p) s += part[p * N3Q + j];
  mod[j] = s;
}

// ---------------- K2: layernorm + modulate -> x_mod bf16 --------------------
__global__ __launch_bounds__(256) void ln_mod_k(
    const float* __restrict__ x, const float* __restrict__ mod,
    bf16* __restrict__ xm) {
  __shared__ float sb[4];
  int l = blockIdx.x, t = threadIdx.x;
  const float* xr = x + (size_t)l * HIDD;
  float4 v[3];
  float s = 0.f;
#pragma unroll
  for (int p = 0; p < 3; ++p) {
    v[p] = *(const float4*)(xr + p * 1024 + t * 4);
    s += v[p].x + v[p].y + v[p].z + v[p].w;
  }
#pragma unroll
  for (int o = 32; o >= 1; o >>= 1) s += __shfl_xor(s, o);
  if (!(t & 63)) sb[t >> 6] = s;
  __syncthreads();
  float mean = (sb[0] + sb[1] + sb[2] + sb[3]) * (1.f / HIDD);
  __syncthreads();
  float vs = 0.f;
#pragma unroll
  for (int p = 0; p < 3; ++p) {
    float a = v[p].x - mean, b = v[p].y - mean, c = v[p].z - mean,
          d = v[p].w - mean;
    vs += a * a + b * b + c * c + d * d;
  }
#pragma unroll
  for (int o = 32; o >= 1; o >>= 1) vs += __shfl_xor(vs, o);
  if (!(t & 63)) sb[t >> 6] = vs;
  __syncthreads();
  float var = (sb[0] + sb[1] + sb[2] + sb[3]) * (1.f / HIDD);
  float rs = rsqrtf(var + 1e-6f);
#pragma unroll
  for (int p = 0; p < 3; ++p) {
    int j = p * 1024 + t * 4;
    float4 sc = *(const float4*)(mod + HIDD + j);
    float4 sh = *(const float4*)(mod + j);
    bf16x4 o;
    o[0] = (bf16)((v[p].x - mean) * rs * (1.f + sc.x) + sh.x);
    o[1] = (bf16)((v[p].y - mean) * rs * (1.f + sc.y) + sh.y);
    o[2] = (bf16)((v[p].z - mean) * rs * (1.f + sc.z) + sh.z);
    o[3] = (bf16)((v[p].w - mean) * rs * (1.f + sc.w) + sh.w);
    *(bf16x4*)(xm + (size_t)l * HIDD + j) = o;
  }
}

// ---------------- convT: src [K][N] f32 -> dst [N'][K] bf16 -----------------
// pad 73 — read bank = (4c + floor((73j+nr)/2)) mod 32, conflict-free.
__global__ __launch_bounds__(256) void convT(
    const float* __restrict__ src, bf16* __restrict__ dst, int K, int N) {
  __shared__ bf16 tl[64 * 73];
  int n0 = blockIdx.x * 64, k0 = blockIdx.y * 64;
  int t = threadIdx.x;
#pragma unroll
  for (int p = 0; p < 4; ++p) {
    int idx = p * 256 + t;
    int kr = idx >> 4, c4 = (idx & 15) << 2;
    float4 v = *(const float4*)(src + (size_t)(k0 + kr) * N + n0 + c4);
    bf16x4 b;
    b[0] = (bf16)v.x; b[1] = (bf16)v.y; b[2] = (bf16)v.z; b[3] = (bf16)v.w;
    *(bf16x4*)(tl + kr * 73 + c4) = b;
  }
  __syncthreads();
#pragma unroll
  for (int p = 0; p < 2; ++p) {
    int idx = p * 256 + t;
    int nr = idx >> 3, c = idx & 7;
    bf16x8 o;
#pragma unroll
    for (int j = 0; j < 8; ++j) o[j] = tl[(c * 8 + j) * 73 + nr];
    *(bf16x8*)(dst + (size_t)(n0 + nr) * K + k0 + c * 8) = o;
  }
}

// ---------------- GEMM 256x256, BK=64, 8 waves, quadrant 8-phase ------------
// EPI=2: combined qkv+fc1 (gy=84): by<36 -> raw bf16 (stride 9216) to dst.p[0];
//        by>=36 -> bias+gelu (stride 12288) to o1. B base: BT/BT2/BT3.
// EPI=3: combined out-proj+fc2 (gy=12, gz=5): bz=0 -> A,BT (lda 3072),
//        f32 acc -> o32 (stride 3072); bz>=1 -> A=BT3 (mlpF, lda 12288,
//        kb=(bz-1)*3072), B=BT2, bf16 partial -> dst.p[bz-1] (stride 3072).
template <int EPI>
__global__ __launch_bounds__(512, 2) void gemm256(
    const bf16* __restrict__ A, const bf16* __restrict__ BT,
    const float* __restrict__ bias, int lda, int klen, int gy, int gz,
    PB dst, bf16* __restrict__ o1, const bf16* __restrict__ BT2,
    const bf16* __restrict__ BT3, float* __restrict__ o32) {
  __shared__ bf16 LA[2][2][8192];   // [buf][half: 128 rows x 64 k]
  __shared__ bf16 LB[2][2][8192];
  const int tid = threadIdx.x;
  const int w = tid >> 6, lane = tid & 63;
  const int wm = w >> 2, wn = w & 3;
  const int g = lane >> 4, r16 = lane & 15;
  const int hb = wn >> 1, brow = (wn & 1) * 64;

  // T1: bijective chunked XCD swizzle (grid % 8 == 0 guaranteed)
  const int nwg = 8 * gy * gz;
  int id = (int)blockIdx.x;
  int sw = (id & 7) * (nwg >> 3) + (id >> 3);
  const int bx = sw & 7;
  const int rem = sw >> 3;
  const int by = rem % gy;
  const int bz = rem / gy;

  const int row0 = bx * 256, col0 = by * 256;

  const int s_r = tid >> 3, s_c = tid & 7;
  const int swzoff = (s_c ^ (s_r & 7)) << 3;

  int lda_eff = lda;
  const bf16* Abase = A;
  const bf16* Bbase = BT;
  size_t kb2 = 0;
  int bcol = col0;
  if (EPI == 2) {
    if (by >= 36)      { Bbase = BT3; bcol = col0 - 9216; }
    else if (by >= 32) { Bbase = BT2; bcol = col0 - 8192; }
  } else if (EPI == 3) {
    if (bz != 0) {
      lda_eff = MLPD;
      Abase = BT3;            // mlpF (fc2 A)
      Bbase = BT2;            // w_fc2^T
      kb2 = (size_t)(bz - 1) * 3072;
    }
  }
  const bf16* gA = Abase + (size_t)(row0 + s_r) * lda_eff + kb2 + swzoff;
  const bf16* gB = Bbase + (size_t)(bcol + s_r) * lda_eff + kb2 + swzoff;
  const int wofs = w * 512;

#define STG_A(buf, h, t)                                                       \
  do {                                                                         \
    gload_lds16(gA + (size_t)((h) * 128) * lda_eff + (size_t)(t) * 64,         \
                &LA[buf][h][wofs]);                                            \
    gload_lds16(gA + (size_t)((h) * 128 + 64) * lda_eff + (size_t)(t) * 64,    \
                &LA[buf][h][4096 + wofs]);                                     \
  } while (0)
#define STG_B(buf, h, t)                                                       \
  do {                                                                         \
    gload_lds16(gB + (size_t)((h) * 128) * lda_eff + (size_t)(t) * 64,         \
                &LB[buf][h][wofs]);                                            \
    gload_lds16(gB + (size_t)((h) * 128 + 64) * lda_eff + (size_t)(t) * 64,    \
                &LB[buf][h][4096 + wofs]);                                     \
  } while (0)
#define RD_A4(DST, LAP, MB)                                                    \
  _Pragma("unroll") for (int m_ = 0; m_ < 4; ++m_)                             \
  _Pragma("unroll") for (int kk_ = 0; kk_ < 2; ++kk_)                          \
      DST[m_][kk_] = *(const bf16x8*)((LAP) + (((MB) + m_) * 16 + r16) * 64 +  \
                                      (((kk_ * 4 + g) ^ (r16 & 7)) << 3));
#define RD_B2(DST, LBP, NB)                                                    \
  _Pragma("unroll") for (int n_ = 0; n_ < 2; ++n_)                             \
  _Pragma("unroll") for (int kk_ = 0; kk_ < 2; ++kk_)                          \
      DST[n_][kk_] = *(const bf16x8*)(                                         \
          (LBP) + (brow + ((NB) + n_) * 16 + r16) * 64 +                       \
          (((kk_ * 4 + g) ^ (r16 & 7)) << 3));
#define QUAD(AF, BF, MB, NB)                                                   \
  do {                                                                         \
    __builtin_amdgcn_s_setprio(1);                                             \
    _Pragma("unroll") for (int kk_ = 0; kk_ < 2; ++kk_)                        \
    _Pragma("unroll") for (int m_ = 0; m_ < 4; ++m_)                           \
    _Pragma("unroll") for (int n_ = 0; n_ < 2; ++n_)                           \
        acc[(MB) + m_][(NB) + n_] = __builtin_amdgcn_mfma_f32_16x16x32_bf16(   \
            AF[m_][kk_], BF[n_][kk_], acc[(MB) + m_][(NB) + n_], 0, 0, 0);     \
    __builtin_amdgcn_s_setprio(0);                                             \
  } while (0)

  // Race-free stage ring. Cross-wave safety = mem-op ISSUE order (barriers
  // order ds_read/stage issue; an issued read cannot be corrupted by a
  // stage-write that arrives later). MFMAs are free to float.
  //   a: B1(T1)->TB^1   b: (none)   c: A0(T2),A1(T2)->TB   d: B0(T2)->TB
#define GROUP(TB, T1, T2)                                                      \
  do {                                                                         \
    const bf16* la = &LA[TB][wm][0];                                           \
    const bf16* lb = &LB[TB][hb][0];                                           \
    bf16x8 aL[4][2], aH[4][2], bL[2][2], bH[2][2];                             \
    /* P-a: 12 ds_reads, stage B1(T1) */                                       \
    RD_A4(aL, la, 0);                                                          \
    RD_B2(bL, lb, 0);                                                          \
    if ((T1) < nk) STG_B(TB ^ 1, 1, T1);                                       \
    __builtin_amdgcn_s_barrier();                                              \
    QUAD(aL, bL, 0, 0);                                                        \
    __builtin_amdgcn_s_barrier();                                              \
    /* P-b: 8 ds_reads, no stage (LA[TB] still being read) */                  \
    RD_A4(aH, la, 4);                                                          \
    __builtin_amdgcn_s_barrier();                                              \
    QUAD(aH, bL, 4, 0);                                                        \
    __builtin_amdgcn_s_barrier();                                              \
    /* P-c: 4 ds_reads, stage A0(T2),A1(T2) */                                 \
    RD_B2(bH, lb, 2);                                                          \
    if ((T2) < nk) { STG_A(TB, 0, T2); STG_A(TB, 1, T2); }                     \
    __builtin_amdgcn_s_barrier();                                              \
    QUAD(aL, bH, 0, 2);                                                        \
    __builtin_amdgcn_s_barrier();                                              \
    /* P-d: no reads, stage B0(T2), counted vmcnt */                           \
    if ((T2) < nk) {                                                           \
      STG_B(TB, 0, T2);                                                        \
      asm volatile("s_waitcnt vmcnt(6)" ::: "memory");                         \
    } else {                                                                   \
      asm volatile("s_waitcnt vmcnt(0)" ::: "memory");                         \
    }                                                                          \
    __builtin_amdgcn_s_barrier();                                              \
    QUAD(aH, bH, 4, 2);                                                        \
    __builtin_amdgcn_s_barrier();                                              \
  } while (0)

  f32x4 acc[8][4] = {};
  const int nk = klen >> 6;   // 48 for all call sites

  // prologue: tile0 complete + A0,A1,B0 of tile1 (B1(1) staged at first P-a);
  // vmcnt(6) waits 14-6=8 oldest = ALL of tile0.
  STG_A(0, 0, 0); STG_A(0, 1, 0); STG_B(0, 0, 0); STG_B(0, 1, 0);
  STG_A(1, 0, 1); STG_A(1, 1, 1); STG_B(1, 0, 1);
  asm volatile("s_waitcnt vmcnt(6)" ::: "memory");
  __builtin_amdgcn_s_barrier();

  for (int t = 0; t < nk; t += 2) {
    GROUP(0, t + 1, t + 2);
    GROUP(1, t + 2, t + 3);
  }
#undef STG_A
#undef STG_B
#undef RD_A4
#undef RD_B2
#undef QUAD
#undef GROUP

  if (EPI == 2 && by < 36) {
    // qkv half: raw bf16, stride 9216
    bf16* dp = dst.p[0];
#pragma unroll
    for (int m = 0; m < 8; ++m) {
      int row = row0 + wm * 128 + m * 16 + g * 4;
#pragma unroll
      for (int n = 0; n < 4; ++n) {
        int col = col0 + wn * 64 + n * 16 + r16;
#pragma unroll
        for (int r = 0; r < 4; ++r)
          dp[(size_t)(row + r) * N3Q + col] = (bf16)acc[m][n][r];
      }
    }
  } else if (EPI == 2) {
    // fc1 half: bias+gelu, stride 12288
    bf16* dp = o1;
#pragma unroll
    for (int m = 0; m < 8; ++m) {
      int row = row0 + wm * 128 + m * 16 + g * 4;
#pragma unroll
      for (int n = 0; n < 4; ++n) {
        int col = col0 - 9216 + wn * 64 + n * 16 + r16;
        float bv = bias[col];
#pragma unroll
        for (int r = 0; r < 4; ++r)
          dp[(size_t)(row + r) * MLPD + col] = (bf16)gelu_tanh(acc[m][n][r] + bv);
      }
    }
  } else if (EPI == 3 && bz == 0) {
    // out-proj: raw f32 sums -> o32 (final adds b_out)
#pragma unroll
    for (int m = 0; m < 8; ++m) {
      int row = row0 + wm * 128 + m * 16 + g * 4;
#pragma unroll
      for (int n = 0; n < 4; ++n) {
        int col = col0 + wn * 64 + n * 16 + r16;
#pragma unroll
        for (int r = 0; r < 4; ++r)
          o32[(size_t)(row + r) * HIDD + col] = acc[m][n][r];
      }
    }
  } else {
    // fc2 partial bz-1: bf16, stride 3072
    bf16* dp = dst.p[bz - 1];
#pragma unroll
    for (int m = 0; m < 8; ++m) {
      int row = row0 + wm * 128 + m * 16 + g * 4;
#pragma unroll
      for (int n = 0; n < 4; ++n) {
        int col = col0 + wn * 64 + n * 16 + r16;
#pragma unroll
        for (int r = 0; r < 4; ++r)
          dp[(size_t)(row + r) * HIDD + col] = (bf16)acc[m][n][r];
      }
    }
  }
}

// ---------------- qknorm+rope from raw qkv (adds b_qkv) ---------------------
__global__ __launch_bounds__(256) void qknorm_rope_k(
    const bf16* __restrict__ P, const float* __restrict__ b_qkv,
    const float* __restrict__ pe, const float* __restrict__ qw,
    const float* __restrict__ kw, bf16* __restrict__ qb,
    bf16* __restrict__ kb) {
  int t = threadIdx.x, lane = t & 63, w = t >> 6;
  int pair = blockIdx.x * 4 + w;
  int h = pair % NHH, l = pair / NHH;
  size_t qi = (size_t)l * N3Q + h * HDD + 2 * lane;
  size_t ob = (size_t)l * HIDD + h * HDD + 2 * lane;
  float4 f = *(const float4*)(pe + (size_t)l * 256 + lane * 4);
  float2 wq = *(const float2*)(qw + 2 * lane);
  float2 wk = *(const float2*)(kw + 2 * lane);
  {
    bf16x2 a = *(const bf16x2*)(P + qi);
    float2 bq = *(const float2*)(b_qkv + h * HDD + 2 * lane);
    float x0 = (float)a[0] + bq.x;
    float x1 = (float)a[1] + bq.y;
    float ss = x0 * x0 + x1 * x1;
#pragma unroll
    for (int o = 32; o >= 1; o >>= 1) ss += __shfl_xor(ss, o);
    float rs = rsqrtf(ss * (1.f / HDD) + 1.1920929e-7f);
    x0 *= rs * wq.x; x1 *= rs * wq.y;
    const float qs = 0.08838834764831845f;  // 1/sqrt(128)
    bf16x2 ov;
    ov[0] = (bf16)((f.x * x0 + f.y * x1) * qs);
    ov[1] = (bf16)((f.z * x0 + f.w * x1) * qs);
    *(bf16x2*)(qb + ob) = ov;
  }
  {
    bf16x2 a = *(const bf16x2*)(P + qi + HIDD);
    float2 bk = *(const float2*)(b_qkv + HIDD + h * HDD + 2 * lane);
    float x0 = (float)a[0] + bk.x;
    float x1 = (float)a[1] + bk.y;
    float ss = x0 * x0 + x1 * x1;
#pragma unroll
    for (int o = 32; o >= 1; o >>= 1) ss += __shfl_xor(ss, o);
    float rs = rsqrtf(ss * (1.f / HDD) + 1.1920929e-7f);
    x0 *= rs * wk.x; x1 *= rs * wk.y;
    bf16x2 ov;
    ov[0] = (bf16)(f.x * x0 + f.y * x1);
    ov[1] = (bf16)(f.z * x0 + f.w * x1);
    *(bf16x2*)(kb + ob) = ov;
  }
}

// ---------------- V transpose from raw qkv: -> vt[h][d][l] ------------------
__global__ __launch_bounds__(256) void vtrans_k(
    const bf16* __restrict__ P, const float* __restrict__ b_qkv,
    bf16* __restrict__ vt) {
  __shared__ bf16 tl[128 * 128];
  int t = threadIdx.x, lt = blockIdx.x, h = blockIdx.y;
#pragma unroll
  for (int p = 0; p < 8; ++p) {
    int idx = p * 256 + t;
    int i = idx >> 4, c = idx & 15;
    size_t gi = (size_t)(lt * 128 + i) * N3Q + 2 * HIDD + h * HDD + c * 8;
    bf16x8 a = *(const bf16x8*)(P + gi);
    bf16x8 val;
#pragma unroll
    for (int e = 0; e < 8; ++e)
      val[e] = (bf16)((float)a[e] + b_qkv[2 * HIDD + h * HDD + c * 8 + e]);
    *(bf16x8*)(tl + i * 128 + ((c ^ (i & 15)) << 3)) = val;
  }
  __syncthreads();
#pragma unroll
  for (int p = 0; p < 8; ++p) {
    int idx = p * 256 + t;
    int j = idx >> 4, i8 = (idx & 15) << 3;
    bf16x8 o;
#pragma unroll
    for (int e = 0; e < 8; ++e) {
      int row = i8 + e;
      o[e] = tl[row * 128 + ((((j >> 3) ^ (row & 15)) << 3) | (j & 7))];
    }
    *(bf16x8*)(vt + ((size_t)h * HDD + j) * L_SEQ + lt * 128 + i8) = o;
  }
}

// ---------------- Flash attention: 4 waves x 16 q-rows, KV tile 64 ----------
__global__ __launch_bounds__(256) void attn_k(
    const bf16* __restrict__ q, const bf16* __restrict__ k,
    const bf16* __restrict__ vt, bf16* __restrict__ out) {
  __shared__ bf16 Ks[64 * 128];
  __shared__ bf16 Vs[128 * 64];
  __shared__ bf16 Ps[4][16 * 72];
  int tid = threadIdx.x, lane = tid & 63, w = tid >> 6;
  int g = lane >> 4, r16 = lane & 15;
  int qt = blockIdx.x, h = blockIdx.y;
  int qbase = qt * 64 + w * 16;

  bf16x8 qreg[4];
  const bf16* qrow = q + (size_t)(qbase + r16) * HIDD + h * HDD;
#pragma unroll
  for (int c = 0; c < 4; ++c) qreg[c] = *(const bf16x8*)(qrow + c * 32 + g * 8);

  f32x4 acc[8] = {};
  float m_run = -3.0e38f, l_run = 0.f;
  bf16* ps = &Ps[w][0];

  for (int kv0 = 0; kv0 < L_SEQ; kv0 += 64) {
    __syncthreads();
#pragma unroll
    for (int p = 0; p < 4; ++p) {
      int ci = p * 256 + tid;
      {
        int rr = ci >> 4, cc = ci & 15;
        gload_lds16(k + (size_t)(kv0 + rr) * HIDD + h * HDD +
                        ((cc ^ (rr & 15)) << 3),
                    Ks + ((p * 4 + w) << 9));
      }
      {
        int rr = ci >> 3, cc = ci & 7;
        gload_lds16(vt + ((size_t)h * HDD + rr) * L_SEQ + kv0 +
                        ((cc ^ (rr & 7)) << 3),
                    Vs + ((p * 4 + w) << 9));
      }
    }
    __syncthreads();

    f32x4 st[4] = {};
#pragma unroll
    for (int m4 = 0; m4 < 4; ++m4) {
#pragma unroll
      for (int c = 0; c < 4; ++c) {
        int rr = m4 * 16 + r16;
        bf16x8 kf =
            *(const bf16x8*)(Ks + rr * 128 + (((c * 4 + g) ^ (rr & 15)) << 3));
        st[m4] =
            __builtin_amdgcn_mfma_f32_16x16x32_bf16(kf, qreg[c], st[m4], 0, 0, 0);
      }
    }
    float cmax = -3.0e38f;
#pragma unroll
    for (int m4 = 0; m4 < 4; ++m4)
#pragma unroll
      for (int r = 0; r < 4; ++r) cmax = fmaxf(cmax, st[m4][r]);
    cmax = fmaxf(cmax, __shfl_xor(cmax, 16));
    cmax = fmaxf(cmax, __shfl_xor(cmax, 32));
    float m_new = fmaxf(m_run, cmax);
    float corr = __expf(m_run - m_new);
    float psum = 0.f;
#pragma unroll
    for (int m4 = 0; m4 < 4; ++m4) {
      bf16x4 pk;
#pragma unroll
      for (int r = 0; r < 4; ++r) {
        float pv = __expf(st[m4][r] - m_new);
        psum += pv;
        pk[r] = (bf16)pv;
      }
      *(bf16x4*)(ps + r16 * 72 + m4 * 16 + g * 4) = pk;
    }
    psum += __shfl_xor(psum, 16);
    psum += __shfl_xor(psum, 32);
    l_run = l_run * corr + psum;
    m_run = m_new;
    float corr_r[4];
#pragma unroll
    for (int r = 0; r < 4; ++r) corr_r[r] = __shfl(corr, g * 4 + r);
#pragma unroll
    for (int nt = 0; nt < 8; ++nt)
#pragma unroll
      for (int r = 0; r < 4; ++r) acc[nt][r] *= corr_r[r];
#pragma unroll
    for (int ks = 0; ks < 2; ++ks) {
      bf16x8 pf = *(const bf16x8*)(ps + r16 * 72 + ks * 32 + g * 8);
#pragma unroll
      for (int nt = 0; nt < 8; ++nt) {
        int rr = nt * 16 + r16;
        bf16x8 vf =
            *(const bf16x8*)(Vs + rr * 64 + (((ks * 4 + g) ^ (rr & 7)) << 3));
        acc[nt] = __builtin_amdgcn_mfma_f32_16x16x32_bf16(pf, vf, acc[nt], 0, 0, 0);
      }
    }
  }
  float inv = 1.f / l_run;
  float inv_r[4];
#pragma unroll
  for (int r = 0; r < 4; ++r) inv_r[r] = __shfl(inv, g * 4 + r);
#pragma unroll
  for (int nt = 0; nt < 8; ++nt)
#pragma unroll
    for (int r = 0; r < 4; ++r)
      out[(size_t)(qbase + g * 4 + r) * HIDD + h * HDD + nt * 16 + r16] =
          (bf16)(acc[nt][r] * inv_r[r]);
}

// -------- final: out = x + gate*(dacc + b_out + sum4(pF) + b_fc2) -----------
__global__ __launch_bounds__(256) void final_k(
    const float* __restrict__ x, PB ps, const float* __restrict__ mod,
    const float* __restrict__ b_out, const float* __restrict__ b_fc2,
    float* __restrict__ out) {
  int l = blockIdx.x, t = threadIdx.x;
#pragma unroll
  for (int p = 0; p < 3; ++p) {
    int c = p * 1024 + t * 4;
    size_t idx = (size_t)l * HIDD + c;
    float4 xv = *(const float4*)(x + idx);
    float4 gv = *(const float4*)(mod + 2 * HIDD + c);
    float4 bo = *(const float4*)(b_out + c);
    float4 bf = *(const float4*)(b_fc2 + c);
    float4 da = *(const float4*)(out + idx);  // out-proj blocks wrote here
    float a0 = da.x + bo.x + bf.x, a1 = da.y + bo.y + bf.y;
    float a2 = da.z + bo.z + bf.z, a3 = da.w + bo.w + bf.w;
#pragma unroll
    for (int i = 0; i < 4; ++i) {
      bf16x4 v = *(const bf16x4*)(ps.p[i] + idx);
      a0 += (float)v[0]; a1 += (float)v[1];
      a2 += (float)v[2]; a3 += (float)v[3];
    }
    float4 o;
    o.x = xv.x + gv.x * a0;
    o.y = xv.y + gv.y * a1;
    o.z = xv.z + gv.z * a2;
    o.w = xv.w + gv.w * a3;
    *(float4*)(out + idx) = o;
  }
}

// ---------------------------------------------------------------------------
extern "C" void kernel_launch(void* const* d_in, const int* in_sizes, int n_in,
                              void* d_out, int out_size, void* d_ws,
                              size_t ws_size, hipStream_t stream) {
  const float* x     = (const float*)d_in[0];
  const float* vec   = (const float*)d_in[1];
  const float* pe    = (const float*)d_in[2];
  const float* w_mod = (const float*)d_in[3];
  const float* b_mod = (const float*)d_in[4];
  const float* w_qkv = (const float*)d_in[5];
  const float* b_qkv = (const float*)d_in[6];
  const float* w_fc1 = (const float*)d_in[7];
  const float* b_fc1 = (const float*)d_in[8];
  const float* w_fc2 = (const float*)d_in[9];
  const float* b_fc2 = (const float*)d_in[10];
  const float* w_out = (const float*)d_in[11];
  const float* b_out = (const float*)d_in[12];
  const float* qw    = (const float*)d_in[13];
  const float* kw    = (const float*)d_in[14];
  float* out = (float*)d_out;

  char* ws = (char*)d_ws;
  float* mod  = (float*)(ws + 0);               // 36864 (pad to 64K)
  bf16* xmod  = (bf16*)(ws + 65536);            // A: 12.58M -> 12648448
  bf16* qb    = (bf16*)(ws + 12648448);         // B
  bf16* kbuf  = (bf16*)(ws + 25231360);         // C
  bf16* vt    = (bf16*)(ws + 37814272);         // D
  bf16* att   = (bf16*)(ws + 50397184);         // E
  bf16* mlpF  = (bf16*)(ws + 62980096);         // F: 50.33M -> 113311744
  bf16* wt    = (bf16*)(ws + 113311744);        // G: 75.5M  -> 188809216
  bf16* P0    = (bf16*)(ws + 188809216);        // H: 37.75M -> 226557952
  float* part = (float*)(ws + 188809216);       // overlay H (early)
  bf16* wtQlo = qb;                             // B..E span: 8192 rows x 3072
  bf16* wtScr = (bf16*)out;                     // d_out scratch: 1024 rows
  bf16* wtO   = P0;                             // H-head: w_out^T (18.9 MB)

  mod_partial<<<dim3(36, 12), 256, 0, stream>>>(vec, w_mod, part);
  mod_reduce<<<36, 256, 0, stream>>>(part, b_mod, mod);
  ln_mod_k<<<2048, 256, 0, stream>>>(x, mod, xmod);

  // ---- combined qkv+fc1: B^T segments -> wtQlo (cols 0..8191),
  //      wtScr (cols 8192..9215, in dead d_out), wt=G (fc1) ----
  convT<<<dim3(128, 48), 256, 0, stream>>>(w_qkv, wtQlo, 3072, 9216);
  convT<<<dim3(16, 48), 256, 0, stream>>>(w_qkv + 8192, wtScr, 3072, 9216);
  convT<<<dim3(192, 48), 256, 0, stream>>>(w_fc1, wt, 3072, 12288);
  PB Pc = {}; Pc.p[0] = P0;
  gemm256<2><<<672, 512, 0, stream>>>(xmod, wtQlo, b_fc1, 3072, 3072, 84, 1,
                                      Pc, mlpF, wtScr, wt, nullptr);

  qknorm_rope_k<<<12288, 256, 0, stream>>>(P0, b_qkv, pe, qw, kw, qb, kbuf);
  vtrans_k<<<dim3(16, 24), 256, 0, stream>>>(P0, b_qkv, vt);
  attn_k<<<dim3(32, 24), 256, 0, stream>>>(qb, kbuf, vt, att);

  // ---- combined out-proj + fc2 (uniform nk=48, 480 blocks):
  //      w_out^T -> H-head (P0 dead after vtrans); w_fc2^T -> G ----
  convT<<<dim3(48, 48), 256, 0, stream>>>(w_out, wtO, 3072, 3072);
  convT<<<dim3(48, 192), 256, 0, stream>>>(w_fc2, wt, 12288, 3072);
  PB Pf = {};
  Pf.p[0] = xmod; Pf.p[1] = qb; Pf.p[2] = kbuf; Pf.p[3] = vt;
  gemm256<3><<<480, 512, 0, stream>>>(att, wtO, nullptr, 3072, 3072, 12, 5,
                                      Pf, nullptr, wt, mlpF, out);

  final_k<<<2048, 256, 0, stream>>>(x, Pf, mod, b_out, b_fc2, out);
}

// Round 15
// 806.460 us; speedup vs baseline: 1.0062x; 1.0058x over previous
//
#include <hip/hip_runtime.h>
#include <hip/hip_bf16.h>
#include <stdint.h>

// ---------------------------------------------------------------------------
// FluxSingleStreamBlock  B=1 L=2048 HID=3072 NH=24 HD=128 MLP=12288
// GEMM: 256x256 tile, BK=64, 8 waves, quadrant 8-phase schedule with
// race-free stage ring: a:B1(t+1) b:- c:A0,A1(t+2) d:B0(t+2)+vmcnt(6).
// Base = R12 (best measured: 809.8us). R15: + T5 setprio around attention's
// QK^T and PV MFMA clusters (m191-verified +4-7% on attn-class kernels).
// Structural note: GEMM wall = MFMA-pipe (~2500cy) + LDS-read pipe (~2300cy)
// serialized per 64-K-tile; 5 schedule variants all converge here (~800 TF).
// ---------------------------------------------------------------------------

typedef __bf16 bf16;
typedef bf16 bf16x2 __attribute__((ext_vector_type(2)));
typedef bf16 bf16x4 __attribute__((ext_vector_type(4)));
typedef bf16 bf16x8 __attribute__((ext_vector_type(8)));
typedef float f32x4 __attribute__((ext_vector_type(4)));

#define L_SEQ 2048
#define HIDD  3072
#define NHH   24
#define HDD   128
#define MLPD  12288
#define N3Q   9216

struct PB { bf16* p[4]; };

__device__ __forceinline__ void gload_lds16(const bf16* g, bf16* l) {
  __builtin_amdgcn_global_load_lds(
      (const __attribute__((address_space(1))) unsigned int*)g,
      (__attribute__((address_space(3))) unsigned int*)l, 16, 0, 0);
}

__device__ __forceinline__ float gelu_tanh(float x) {
  float z = 0.7978845608028654f * (x + 0.044715f * x * x * x);
  float t = 1.f - 2.f / (__expf(2.f * z) + 1.f);   // tanh(z), inf-safe
  return 0.5f * x * (1.f + t);
}

// ---------------- K1a: mod partial GEMV: silu(vec) @ w_mod ------------------
__global__ __launch_bounds__(256) void mod_partial(
    const float* __restrict__ vec, const float* __restrict__ w_mod,
    float* __restrict__ part) {
  __shared__ float sv[256];
  int y = blockIdx.y;
  int i0 = y * 256;
  {
    float xv = vec[i0 + threadIdx.x];
    sv[threadIdx.x] = xv / (1.f + __expf(-xv));
  }
  __syncthreads();
  int j = blockIdx.x * 256 + threadIdx.x;
  float acc = 0.f;
#pragma unroll 8
  for (int i = 0; i < 256; ++i)
    acc += sv[i] * w_mod[(size_t)(i0 + i) * N3Q + j];
  part[y * N3Q + j] = acc;
}

__global__ __launch_bounds__(256) void mod_reduce(
    const float* __restrict__ part, const float* __restrict__ b_mod,
    float* __restrict__ mod) {
  int j = blockIdx.x * 256 + threadIdx.x;
  float s = b_mod[j];
#pragma unroll
  for (int p = 0; p < 12; ++p) s += part[p * N3Q + j];
  mod[j] = s;
}

// ---------------- K2: layernorm + modulate -> x_mod bf16 --------------------
__global__ __launch_bounds__(256) void ln_mod_k(
    const float* __restrict__ x, const float* __restrict__ mod,
    bf16* __restrict__ xm) {
  __shared__ float sb[4];
  int l = blockIdx.x, t = threadIdx.x;
  const float* xr = x + (size_t)l * HIDD;
  float4 v[3];
  float s = 0.f;
#pragma unroll
  for (int p = 0; p < 3; ++p) {
    v[p] = *(const float4*)(xr + p * 1024 + t * 4);
    s += v[p].x + v[p].y + v[p].z + v[p].w;
  }
#pragma unroll
  for (int o = 32; o >= 1; o >>= 1) s += __shfl_xor(s, o);
  if (!(t & 63)) sb[t >> 6] = s;
  __syncthreads();
  float mean = (sb[0] + sb[1] + sb[2] + sb[3]) * (1.f / HIDD);
  __syncthreads();
  float vs = 0.f;
#pragma unroll
  for (int p = 0; p < 3; ++p) {
    float a = v[p].x - mean, b = v[p].y - mean, c = v[p].z - mean,
          d = v[p].w - mean;
    vs += a * a + b * b + c * c + d * d;
  }
#pragma unroll
  for (int o = 32; o >= 1; o >>= 1) vs += __shfl_xor(vs, o);
  if (!(t & 63)) sb[t >> 6] = vs;
  __syncthreads();
  float var = (sb[0] + sb[1] + sb[2] + sb[3]) * (1.f / HIDD);
  float rs = rsqrtf(var + 1e-6f);
#pragma unroll
  for (int p = 0; p < 3; ++p) {
    int j = p * 1024 + t * 4;
    float4 sc = *(const float4*)(mod + HIDD + j);
    float4 sh = *(const float4*)(mod + j);
    bf16x4 o;
    o[0] = (bf16)((v[p].x - mean) * rs * (1.f + sc.x) + sh.x);
    o[1] = (bf16)((v[p].y - mean) * rs * (1.f + sc.y) + sh.y);
    o[2] = (bf16)((v[p].z - mean) * rs * (1.f + sc.z) + sh.z);
    o[3] = (bf16)((v[p].w - mean) * rs * (1.f + sc.w) + sh.w);
    *(bf16x4*)(xm + (size_t)l * HIDD + j) = o;
  }
}

// ---------------- convT: src [K][N] f32 -> dst [N'][K] bf16 -----------------
// pad 73 — read bank = (4c + floor((73j+nr)/2)) mod 32, conflict-free.
__global__ __launch_bounds__(256) void convT(
    const float* __restrict__ src, bf16* __restrict__ dst, int K, int N) {
  __shared__ bf16 tl[64 * 73];
  int n0 = blockIdx.x * 64, k0 = blockIdx.y * 64;
  int t = threadIdx.x;
#pragma unroll
  for (int p = 0; p < 4; ++p) {
    int idx = p * 256 + t;
    int kr = idx >> 4, c4 = (idx & 15) << 2;
    float4 v = *(const float4*)(src + (size_t)(k0 + kr) * N + n0 + c4);
    bf16x4 b;
    b[0] = (bf16)v.x; b[1] = (bf16)v.y; b[2] = (bf16)v.z; b[3] = (bf16)v.w;
    *(bf16x4*)(tl + kr * 73 + c4) = b;
  }
  __syncthreads();
#pragma unroll
  for (int p = 0; p < 2; ++p) {
    int idx = p * 256 + t;
    int nr = idx >> 3, c = idx & 7;
    bf16x8 o;
#pragma unroll
    for (int j = 0; j < 8; ++j) o[j] = tl[(c * 8 + j) * 73 + nr];
    *(bf16x8*)(dst + (size_t)(n0 + nr) * K + k0 + c * 8) = o;
  }
}

// ---------------- GEMM 256x256, BK=64, 8 waves, quadrant 8-phase ------------
// EPI=2: combined qkv+fc1 (gy=84): by<36 -> raw bf16 (stride 9216) to dst.p[0];
//        by>=36 -> bias+gelu (stride 12288) to o1. B base: BT/BT2/BT3.
// EPI=3: combined out-proj+fc2 (gy=12, gz=5): bz=0 -> A,BT (lda 3072),
//        f32 acc -> o32 (stride 3072); bz>=1 -> A=BT3 (mlpF, lda 12288,
//        kb=(bz-1)*3072), B=BT2, bf16 partial -> dst.p[bz-1] (stride 3072).
template <int EPI>
__global__ __launch_bounds__(512, 2) void gemm256(
    const bf16* __restrict__ A, const bf16* __restrict__ BT,
    const float* __restrict__ bias, int lda, int klen, int gy, int gz,
    PB dst, bf16* __restrict__ o1, const bf16* __restrict__ BT2,
    const bf16* __restrict__ BT3, float* __restrict__ o32) {
  __shared__ bf16 LA[2][2][8192];   // [buf][half: 128 rows x 64 k]
  __shared__ bf16 LB[2][2][8192];
  const int tid = threadIdx.x;
  const int w = tid >> 6, lane = tid & 63;
  const int wm = w >> 2, wn = w & 3;
  const int g = lane >> 4, r16 = lane & 15;
  const int hb = wn >> 1, brow = (wn & 1) * 64;

  // T1: bijective chunked XCD swizzle (grid % 8 == 0 guaranteed)
  const int nwg = 8 * gy * gz;
  int id = (int)blockIdx.x;
  int sw = (id & 7) * (nwg >> 3) + (id >> 3);
  const int bx = sw & 7;
  const int rem = sw >> 3;
  const int by = rem % gy;
  const int bz = rem / gy;

  const int row0 = bx * 256, col0 = by * 256;

  const int s_r = tid >> 3, s_c = tid & 7;
  const int swzoff = (s_c ^ (s_r & 7)) << 3;

  int lda_eff = lda;
  const bf16* Abase = A;
  const bf16* Bbase = BT;
  size_t kb2 = 0;
  int bcol = col0;
  if (EPI == 2) {
    if (by >= 36)      { Bbase = BT3; bcol = col0 - 9216; }
    else if (by >= 32) { Bbase = BT2; bcol = col0 - 8192; }
  } else if (EPI == 3) {
    if (bz != 0) {
      lda_eff = MLPD;
      Abase = BT3;            // mlpF (fc2 A)
      Bbase = BT2;            // w_fc2^T
      kb2 = (size_t)(bz - 1) * 3072;
    }
  }
  const bf16* gA = Abase + (size_t)(row0 + s_r) * lda_eff + kb2 + swzoff;
  const bf16* gB = Bbase + (size_t)(bcol + s_r) * lda_eff + kb2 + swzoff;
  const int wofs = w * 512;

#define STG_A(buf, h, t)                                                       \
  do {                                                                         \
    gload_lds16(gA + (size_t)((h) * 128) * lda_eff + (size_t)(t) * 64,         \
                &LA[buf][h][wofs]);                                            \
    gload_lds16(gA + (size_t)((h) * 128 + 64) * lda_eff + (size_t)(t) * 64,    \
                &LA[buf][h][4096 + wofs]);                                     \
  } while (0)
#define STG_B(buf, h, t)                                                       \
  do {                                                                         \
    gload_lds16(gB + (size_t)((h) * 128) * lda_eff + (size_t)(t) * 64,         \
                &LB[buf][h][wofs]);                                            \
    gload_lds16(gB + (size_t)((h) * 128 + 64) * lda_eff + (size_t)(t) * 64,    \
                &LB[buf][h][4096 + wofs]);                                     \
  } while (0)
#define SB0() __builtin_amdgcn_sched_barrier(0)
#define RD_A4(DST, LAP, MB)                                                    \
  _Pragma("unroll") for (int m_ = 0; m_ < 4; ++m_)                             \
  _Pragma("unroll") for (int kk_ = 0; kk_ < 2; ++kk_)                          \
      DST[m_][kk_] = *(const bf16x8*)((LAP) + (((MB) + m_) * 16 + r16) * 64 +  \
                                      (((kk_ * 4 + g) ^ (r16 & 7)) << 3));
#define RD_B2(DST, LBP, NB)                                                    \
  _Pragma("unroll") for (int n_ = 0; n_ < 2; ++n_)                             \
  _Pragma("unroll") for (int kk_ = 0; kk_ < 2; ++kk_)                          \
      DST[n_][kk_] = *(const bf16x8*)(                                         \
          (LBP) + (brow + ((NB) + n_) * 16 + r16) * 64 +                       \
          (((kk_ * 4 + g) ^ (r16 & 7)) << 3));
#define QUAD(AF, BF, MB, NB)                                                   \
  do {                                                                         \
    __builtin_amdgcn_s_setprio(1);                                             \
    _Pragma("unroll") for (int kk_ = 0; kk_ < 2; ++kk_)                        \
    _Pragma("unroll") for (int m_ = 0; m_ < 4; ++m_)                           \
    _Pragma("unroll") for (int n_ = 0; n_ < 2; ++n_)                           \
        acc[(MB) + m_][(NB) + n_] = __builtin_amdgcn_mfma_f32_16x16x32_bf16(   \
            AF[m_][kk_], BF[n_][kk_], acc[(MB) + m_][(NB) + n_], 0, 0, 0);     \
    __builtin_amdgcn_s_setprio(0);                                             \
  } while (0)

  // Race-free stage ring. Stage-safety via compiler waits: each phase's
  // reads feed same-phase MFMAs, so they drain before the phase-end barrier.
  //   a: B1(T1)->TB^1   b: (none)   c: A0(T2),A1(T2)->TB   d: B0(T2)->TB
#define GROUP(TB, T1, T2)                                                      \
  do {                                                                         \
    const bf16* la = &LA[TB][wm][0];                                           \
    const bf16* lb = &LB[TB][hb][0];                                           \
    bf16x8 aL[4][2], aH[4][2], bL[2][2], bH[2][2];                             \
    /* P-a: 12 ds_reads, stage B1(T1) */                                       \
    RD_A4(aL, la, 0);                                                          \
    RD_B2(bL, lb, 0);                                                          \
    if ((T1) < nk) STG_B(TB ^ 1, 1, T1);                                       \
    __builtin_amdgcn_s_barrier();                                              \
    SB0();                                                                     \
    QUAD(aL, bL, 0, 0);                                                        \
    __builtin_amdgcn_s_barrier();                                              \
    /* P-b: 8 ds_reads, no stage (LA[TB] still being read) */                  \
    RD_A4(aH, la, 4);                                                          \
    __builtin_amdgcn_s_barrier();                                              \
    SB0();                                                                     \
    QUAD(aH, bL, 4, 0);                                                        \
    __builtin_amdgcn_s_barrier();                                              \
    /* P-c: 4 ds_reads, stage A0(T2),A1(T2) (LA[TB] dead since P-b barrier) */ \
    RD_B2(bH, lb, 2);                                                          \
    if ((T2) < nk) { STG_A(TB, 0, T2); STG_A(TB, 1, T2); }                     \
    __builtin_amdgcn_s_barrier();                                              \
    SB0();                                                                     \
    QUAD(aL, bH, 0, 2);                                                        \
    __builtin_amdgcn_s_barrier();                                              \
    /* P-d: no reads, stage B0(T2) (LB[TB] dead since P-c barrier), vmcnt */   \
    if ((T2) < nk) {                                                           \
      STG_B(TB, 0, T2);                                                        \
      asm volatile("s_waitcnt vmcnt(6)" ::: "memory");                         \
    } else {                                                                   \
      asm volatile("s_waitcnt vmcnt(0)" ::: "memory");                         \
    }                                                                          \
    __builtin_amdgcn_s_barrier();                                              \
    SB0();                                                                     \
    QUAD(aH, bH, 4, 2);                                                        \
    __builtin_amdgcn_s_barrier();                                              \
  } while (0)

  f32x4 acc[8][4] = {};
  const int nk = klen >> 6;   // 48 for all call sites

  // prologue: tile0 complete + A0,A1,B0 of tile1 (B1(1) staged at first P-a);
  // vmcnt(6) waits 14-6=8 oldest = ALL of tile0.
  STG_A(0, 0, 0); STG_A(0, 1, 0); STG_B(0, 0, 0); STG_B(0, 1, 0);
  STG_A(1, 0, 1); STG_A(1, 1, 1); STG_B(1, 0, 1);
  asm volatile("s_waitcnt vmcnt(6)" ::: "memory");
  __builtin_amdgcn_s_barrier();

  for (int t = 0; t < nk; t += 2) {
    GROUP(0, t + 1, t + 2);
    GROUP(1, t + 2, t + 3);
  }
#undef STG_A
#undef STG_B
#undef SB0
#undef RD_A4
#undef RD_B2
#undef QUAD
#undef GROUP

  if (EPI == 2 && by < 36) {
    // qkv half: raw bf16, stride 9216
    bf16* dp = dst.p[0];
#pragma unroll
    for (int m = 0; m < 8; ++m) {
      int row = row0 + wm * 128 + m * 16 + g * 4;
#pragma unroll
      for (int n = 0; n < 4; ++n) {
        int col = col0 + wn * 64 + n * 16 + r16;
#pragma unroll
        for (int r = 0; r < 4; ++r)
          dp[(size_t)(row + r) * N3Q + col] = (bf16)acc[m][n][r];
      }
    }
  } else if (EPI == 2) {
    // fc1 half: bias+gelu, stride 12288
    bf16* dp = o1;
#pragma unroll
    for (int m = 0; m < 8; ++m) {
      int row = row0 + wm * 128 + m * 16 + g * 4;
#pragma unroll
      for (int n = 0; n < 4; ++n) {
        int col = col0 - 9216 + wn * 64 + n * 16 + r16;
        float bv = bias[col];
#pragma unroll
        for (int r = 0; r < 4; ++r)
          dp[(size_t)(row + r) * MLPD + col] = (bf16)gelu_tanh(acc[m][n][r] + bv);
      }
    }
  } else if (EPI == 3 && bz == 0) {
    // out-proj: raw f32 sums -> o32 (final adds b_out)
#pragma unroll
    for (int m = 0; m < 8; ++m) {
      int row = row0 + wm * 128 + m * 16 + g * 4;
#pragma unroll
      for (int n = 0; n < 4; ++n) {
        int col = col0 + wn * 64 + n * 16 + r16;
#pragma unroll
        for (int r = 0; r < 4; ++r)
          o32[(size_t)(row + r) * HIDD + col] = acc[m][n][r];
      }
    }
  } else {
    // fc2 partial bz-1: bf16, stride 3072
    bf16* dp = dst.p[bz - 1];
#pragma unroll
    for (int m = 0; m < 8; ++m) {
      int row = row0 + wm * 128 + m * 16 + g * 4;
#pragma unroll
      for (int n = 0; n < 4; ++n) {
        int col = col0 + wn * 64 + n * 16 + r16;
#pragma unroll
        for (int r = 0; r < 4; ++r)
          dp[(size_t)(row + r) * HIDD + col] = (bf16)acc[m][n][r];
      }
    }
  }
}

// ---------------- qknorm+rope from raw qkv (adds b_qkv) ---------------------
__global__ __launch_bounds__(256) void qknorm_rope_k(
    const bf16* __restrict__ P, const float* __restrict__ b_qkv,
    const float* __restrict__ pe, const float* __restrict__ qw,
    const float* __restrict__ kw, bf16* __restrict__ qb,
    bf16* __restrict__ kb) {
  int t = threadIdx.x, lane = t & 63, w = t >> 6;
  int pair = blockIdx.x * 4 + w;
  int h = pair % NHH, l = pair / NHH;
  size_t qi = (size_t)l * N3Q + h * HDD + 2 * lane;
  size_t ob = (size_t)l * HIDD + h * HDD + 2 * lane;
  float4 f = *(const float4*)(pe + (size_t)l * 256 + lane * 4);
  float2 wq = *(const float2*)(qw + 2 * lane);
  float2 wk = *(const float2*)(kw + 2 * lane);
  {
    bf16x2 a = *(const bf16x2*)(P + qi);
    float2 bq = *(const float2*)(b_qkv + h * HDD + 2 * lane);
    float x0 = (float)a[0] + bq.x;
    float x1 = (float)a[1] + bq.y;
    float ss = x0 * x0 + x1 * x1;
#pragma unroll
    for (int o = 32; o >= 1; o >>= 1) ss += __shfl_xor(ss, o);
    float rs = rsqrtf(ss * (1.f / HDD) + 1.1920929e-7f);
    x0 *= rs * wq.x; x1 *= rs * wq.y;
    const float qs = 0.08838834764831845f;  // 1/sqrt(128)
    bf16x2 ov;
    ov[0] = (bf16)((f.x * x0 + f.y * x1) * qs);
    ov[1] = (bf16)((f.z * x0 + f.w * x1) * qs);
    *(bf16x2*)(qb + ob) = ov;
  }
  {
    bf16x2 a = *(const bf16x2*)(P + qi + HIDD);
    float2 bk = *(const float2*)(b_qkv + HIDD + h * HDD + 2 * lane);
    float x0 = (float)a[0] + bk.x;
    float x1 = (float)a[1] + bk.y;
    float ss = x0 * x0 + x1 * x1;
#pragma unroll
    for (int o = 32; o >= 1; o >>= 1) ss += __shfl_xor(ss, o);
    float rs = rsqrtf(ss * (1.f / HDD) + 1.1920929e-7f);
    x0 *= rs * wk.x; x1 *= rs * wk.y;
    bf16x2 ov;
    ov[0] = (bf16)(f.x * x0 + f.y * x1);
    ov[1] = (bf16)(f.z * x0 + f.w * x1);
    *(bf16x2*)(kb + ob) = ov;
  }
}

// ---------------- V transpose from raw qkv: -> vt[h][d][l] ------------------
__global__ __launch_bounds__(256) void vtrans_k(
    const bf16* __restrict__ P, const float* __restrict__ b_qkv,
    bf16* __restrict__ vt) {
  __shared__ bf16 tl[128 * 128];
  int t = threadIdx.x, lt = blockIdx.x, h = blockIdx.y;
#pragma unroll
  for (int p = 0; p < 8; ++p) {
    int idx = p * 256 + t;
    int i = idx >> 4, c = idx & 15;
    size_t gi = (size_t)(lt * 128 + i) * N3Q + 2 * HIDD + h * HDD + c * 8;
    bf16x8 a = *(const bf16x8*)(P + gi);
    bf16x8 val;
#pragma unroll
    for (int e = 0; e < 8; ++e)
      val[e] = (bf16)((float)a[e] + b_qkv[2 * HIDD + h * HDD + c * 8 + e]);
    *(bf16x8*)(tl + i * 128 + ((c ^ (i & 15)) << 3)) = val;
  }
  __syncthreads();
#pragma unroll
  for (int p = 0; p < 8; ++p) {
    int idx = p * 256 + t;
    int j = idx >> 4, i8 = (idx & 15) << 3;
    bf16x8 o;
#pragma unroll
    for (int e = 0; e < 8; ++e) {
      int row = i8 + e;
      o[e] = tl[row * 128 + ((((j >> 3) ^ (row & 15)) << 3) | (j & 7))];
    }
    *(bf16x8*)(vt + ((size_t)h * HDD + j) * L_SEQ + lt * 128 + i8) = o;
  }
}

// ---------------- Flash attention: 4 waves x 16 q-rows, KV tile 64 ----------
__global__ __launch_bounds__(256) void attn_k(
    const bf16* __restrict__ q, const bf16* __restrict__ k,
    const bf16* __restrict__ vt, bf16* __restrict__ out) {
  __shared__ bf16 Ks[64 * 128];
  __shared__ bf16 Vs[128 * 64];
  __shared__ bf16 Ps[4][16 * 72];
  int tid = threadIdx.x, lane = tid & 63, w = tid >> 6;
  int g = lane >> 4, r16 = lane & 15;
  int qt = blockIdx.x, h = blockIdx.y;
  int qbase = qt * 64 + w * 16;

  bf16x8 qreg[4];
  const bf16* qrow = q + (size_t)(qbase + r16) * HIDD + h * HDD;
#pragma unroll
  for (int c = 0; c < 4; ++c) qreg[c] = *(const bf16x8*)(qrow + c * 32 + g * 8);

  f32x4 acc[8] = {};
  float m_run = -3.0e38f, l_run = 0.f;
  bf16* ps = &Ps[w][0];

  for (int kv0 = 0; kv0 < L_SEQ; kv0 += 64) {
    __syncthreads();
#pragma unroll
    for (int p = 0; p < 4; ++p) {
      int ci = p * 256 + tid;
      {
        int rr = ci >> 4, cc = ci & 15;
        gload_lds16(k + (size_t)(kv0 + rr) * HIDD + h * HDD +
                        ((cc ^ (rr & 15)) << 3),
                    Ks + ((p * 4 + w) << 9));
      }
      {
        int rr = ci >> 3, cc = ci & 7;
        gload_lds16(vt + ((size_t)h * HDD + rr) * L_SEQ + kv0 +
                        ((cc ^ (rr & 7)) << 3),
                    Vs + ((p * 4 + w) << 9));
      }
    }
    __syncthreads();

    f32x4 st[4] = {};
    __builtin_amdgcn_s_setprio(1);   // T5: favor QK^T MFMA cluster (m191)
#pragma unroll
    for (int m4 = 0; m4 < 4; ++m4) {
#pragma unroll
      for (int c = 0; c < 4; ++c) {
        int rr = m4 * 16 + r16;
        bf16x8 kf =
            *(const bf16x8*)(Ks + rr * 128 + (((c * 4 + g) ^ (rr & 15)) << 3));
        st[m4] =
            __builtin_amdgcn_mfma_f32_16x16x32_bf16(kf, qreg[c], st[m4], 0, 0, 0);
      }
    }
    __builtin_amdgcn_s_setprio(0);
    float cmax = -3.0e38f;
#pragma unroll
    for (int m4 = 0; m4 < 4; ++m4)
#pragma unroll
      for (int r = 0; r < 4; ++r) cmax = fmaxf(cmax, st[m4][r]);
    cmax = fmaxf(cmax, __shfl_xor(cmax, 16));
    cmax = fmaxf(cmax, __shfl_xor(cmax, 32));
    float m_new = fmaxf(m_run, cmax);
    float corr = __expf(m_run - m_new);
    float psum = 0.f;
#pragma unroll
    for (int m4 = 0; m4 < 4; ++m4) {
      bf16x4 pk;
#pragma unroll
      for (int r = 0; r < 4; ++r) {
        float pv = __expf(st[m4][r] - m_new);
        psum += pv;
        pk[r] = (bf16)pv;
      }
      *(bf16x4*)(ps + r16 * 72 + m4 * 16 + g * 4) = pk;
    }
    psum += __shfl_xor(psum, 16);
    psum += __shfl_xor(psum, 32);
    l_run = l_run * corr + psum;
    m_run = m_new;
    float corr_r[4];
#pragma unroll
    for (int r = 0; r < 4; ++r) corr_r[r] = __shfl(corr, g * 4 + r);
#pragma unroll
    for (int nt = 0; nt < 8; ++nt)
#pragma unroll
      for (int r = 0; r < 4; ++r) acc[nt][r] *= corr_r[r];
    __builtin_amdgcn_s_setprio(1);   // T5: favor PV MFMA cluster
#pragma unroll
    for (int ks = 0; ks < 2; ++ks) {
      bf16x8 pf = *(const bf16x8*)(ps + r16 * 72 + ks * 32 + g * 8);
#pragma unroll
      for (int nt = 0; nt < 8; ++nt) {
        int rr = nt * 16 + r16;
        bf16x8 vf =
            *(const bf16x8*)(Vs + rr * 64 + (((ks * 4 + g) ^ (rr & 7)) << 3));
        acc[nt] = __builtin_amdgcn_mfma_f32_16x16x32_bf16(pf, vf, acc[nt], 0, 0, 0);
      }
    }
    __builtin_amdgcn_s_setprio(0);
  }
  float inv = 1.f / l_run;
  float inv_r[4];
#pragma unroll
  for (int r = 0; r < 4; ++r) inv_r[r] = __shfl(inv, g * 4 + r);
#pragma unroll
  for (int nt = 0; nt < 8; ++nt)
#pragma unroll
    for (int r = 0; r < 4; ++r)
      out[(size_t)(qbase + g * 4 + r) * HIDD + h * HDD + nt * 16 + r16] =
          (bf16)(acc[nt][r] * inv_r[r]);
}

// -------- final: out = x + gate*(dacc + b_out + sum4(pF) + b_fc2) -----------
__global__ __launch_bounds__(256) void final_k(
    const float* __restrict__ x, PB ps, const float* __restrict__ mod,
    const float* __restrict__ b_out, const float* __restrict__ b_fc2,
    float* __restrict__ out) {
  int l = blockIdx.x, t = threadIdx.x;
#pragma unroll
  for (int p = 0; p < 3; ++p) {
    int c = p * 1024 + t * 4;
    size_t idx = (size_t)l * HIDD + c;
    float4 xv = *(const float4*)(x + idx);
    float4 gv = *(const float4*)(mod + 2 * HIDD + c);
    float4 bo = *(const float4*)(b_out + c);
    float4 bf = *(const float4*)(b_fc2 + c);
    float4 da = *(const float4*)(out + idx);  // out-proj blocks wrote here
    float a0 = da.x + bo.x + bf.x, a1 = da.y + bo.y + bf.y;
    float a2 = da.z + bo.z + bf.z, a3 = da.w + bo.w + bf.w;
#pragma unroll
    for (int i = 0; i < 4; ++i) {
      bf16x4 v = *(const bf16x4*)(ps.p[i] + idx);
      a0 += (float)v[0]; a1 += (float)v[1];
      a2 += (float)v[2]; a3 += (float)v[3];
    }
    float4 o;
    o.x = xv.x + gv.x * a0;
    o.y = xv.y + gv.y * a1;
    o.z = xv.z + gv.z * a2;
    o.w = xv.w + gv.w * a3;
    *(float4*)(out + idx) = o;
  }
}

// ---------------------------------------------------------------------------
extern "C" void kernel_launch(void* const* d_in, const int* in_sizes, int n_in,
                              void* d_out, int out_size, void* d_ws,
                              size_t ws_size, hipStream_t stream) {
  const float* x     = (const float*)d_in[0];
  const float* vec   = (const float*)d_in[1];
  const float* pe    = (const float*)d_in[2];
  const float* w_mod = (const float*)d_in[3];
  const float* b_mod = (const float*)d_in[4];
  const float* w_qkv = (const float*)d_in[5];
  const float* b_qkv = (const float*)d_in[6];
  const float* w_fc1 = (const float*)d_in[7];
  const float* b_fc1 = (const float*)d_in[8];
  const float* w_fc2 = (const float*)d_in[9];
  const float* b_fc2 = (const float*)d_in[10];
  const float* w_out = (const float*)d_in[11];
  const float* b_out = (const float*)d_in[12];
  const float* qw    = (const float*)d_in[13];
  const float* kw    = (const float*)d_in[14];
  float* out = (float*)d_out;

  char* ws = (char*)d_ws;
  float* mod  = (float*)(ws + 0);               // 36864 (pad to 64K)
  bf16* xmod  = (bf16*)(ws + 65536);            // A: 12.58M -> 12648448
  bf16* qb    = (bf16*)(ws + 12648448);         // B
  bf16* kbuf  = (bf16*)(ws + 25231360);         // C
  bf16* vt    = (bf16*)(ws + 37814272);         // D
  bf16* att   = (bf16*)(ws + 50397184);         // E
  bf16* mlpF  = (bf16*)(ws + 62980096);         // F: 50.33M -> 113311744
  bf16* wt    = (bf16*)(ws + 113311744);        // G: 75.5M  -> 188809216
  bf16* P0    = (bf16*)(ws + 188809216);        // H: 37.75M -> 226557952
  float* part = (float*)(ws + 188809216);       // overlay H (early)
  bf16* wtQlo = qb;                             // B..E span: 8192 rows x 3072
  bf16* wtScr = (bf16*)out;                     // d_out scratch: 1024 rows
  bf16* wtO   = P0;                             // H-head: w_out^T (18.9 MB)

  mod_partial<<<dim3(36, 12), 256, 0, stream>>>(vec, w_mod, part);
  mod_reduce<<<36, 256, 0, stream>>>(part, b_mod, mod);
  ln_mod_k<<<2048, 256, 0, stream>>>(x, mod, xmod);

  // ---- combined qkv+fc1: B^T segments -> wtQlo (cols 0..8191),
  //      wtScr (cols 8192..9215, in dead d_out), wt=G (fc1) ----
  convT<<<dim3(128, 48), 256, 0, stream>>>(w_qkv, wtQlo, 3072, 9216);
  convT<<<dim3(16, 48), 256, 0, stream>>>(w_qkv + 8192, wtScr, 3072, 9216);
  convT<<<dim3(192, 48), 256, 0, stream>>>(w_fc1, wt, 3072, 12288);
  PB Pc = {}; Pc.p[0] = P0;
  gemm256<2><<<672, 512, 0, stream>>>(xmod, wtQlo, b_fc1, 3072, 3072, 84, 1,
                                      Pc, mlpF, wtScr, wt, nullptr);

  qknorm_rope_k<<<12288, 256, 0, stream>>>(P0, b_qkv, pe, qw, kw, qb, kbuf);
  vtrans_k<<<dim3(16, 24), 256, 0, stream>>>(P0, b_qkv, vt);
  attn_k<<<dim3(32, 24), 256, 0, stream>>>(qb, kbuf, vt, att);

  // ---- combined out-proj + fc2 (uniform nk=48, 480 blocks):
  //      w_out^T -> H-head (P0 dead after vtrans); w_fc2^T -> G ----
  convT<<<dim3(48, 48), 256, 0, stream>>>(w_out, wtO, 3072, 3072);
  convT<<<dim3(48, 192), 256, 0, stream>>>(w_fc2, wt, 12288, 3072);
  PB Pf = {};
  Pf.p[0] = xmod; Pf.p[1] = qb; Pf.p[2] = kbuf; Pf.p[3] = vt;
  gemm256<3><<<480, 512, 0, stream>>>(att, wtO, nullptr, 3072, 3072, 12, 5,
                                      Pf, nullptr, wt, mlpF, out);

  final_k<<<2048, 256, 0, stream>>>(x, Pf, mod, b_out, b_fc2, out);
}